// Round 5
// baseline (204.615 us; speedup 1.0000x reference)
//
#include <hip/hip_runtime.h>
#include <hip/hip_bf16.h>

#define BATCH 16
#define CDIM  512
#define SEQ   1024
#define HEADS 8
#define DHEAD 64
#define N3    1536      // 3 * HEADS * DHEAD
// q pre-scale: dk^-0.5 * log2(e), so attn uses exp2 directly (softmax-invariant)
#define QSCALE 0.18033688011112042f

typedef unsigned short ushort_t;
typedef __attribute__((ext_vector_type(8))) short short8;   // 8 bf16 (4 VGPRs)
typedef __attribute__((ext_vector_type(4))) float f32x4;

// fp32 -> bf16 bits, round-to-nearest-even
__device__ __forceinline__ unsigned f2bf(float f) {
    unsigned u = __float_as_uint(f);
    u += 0x7fffu + ((u >> 16) & 1u);
    return u >> 16;
}
// 2^x via v_exp_f32 (quarter-rate transcendental; inputs are normal-range)
__device__ __forceinline__ float fast_exp2(float x) {
    float r;
    asm("v_exp_f32 %0, %1" : "=v"(r) : "v"(x));
    return r;
}
// pack trunc-bf16(lo), trunc-bf16(hi) -> one u32 via v_perm_b32 (1 VALU op)
__device__ __forceinline__ unsigned pack_bf16_trunc(float lo, float hi) {
    return __builtin_amdgcn_perm(__float_as_uint(hi), __float_as_uint(lo), 0x07060302u);
}
// async global->LDS, 16B/lane; per-lane ptr pre-offset by lane*16B so each
// wave covers 1 KB CONTIGUOUS global memory (one transaction, not 64).
__device__ __forceinline__ void async16(const void* g, void* l) {
    __builtin_amdgcn_global_load_lds(
        (const __attribute__((address_space(1))) unsigned int*)g,
        (__attribute__((address_space(3))) unsigned int*)l, 16, 0, 0);
}
// raw barrier (no vmcnt drain) fenced against compiler reordering
__device__ __forceinline__ void barrier_raw() {
    __builtin_amdgcn_sched_barrier(0);
    __builtin_amdgcn_s_barrier();
    __builtin_amdgcn_sched_barrier(0);
}
// counted vmcnt wait: leaves newest N loads in flight across the barrier (T4)
#define WAIT_VMCNT(n) asm volatile("s_waitcnt vmcnt(" #n ")" ::: "memory")

// ---------------------------------------------------------------------------
// Blocked fragment-order layout for GEMM staging (all staged operands):
//   element (m, k):  mt=m>>7, mr=m&127, m16=mr>>4, col=mr&15,
//                    it=k>>5, q=(k>>3)&3, j=k&7
//   off = ((mt*16+it)*8 + m16)*512 + (q*16+col)*8 + j
// One (mt,it,m16) chunk = 512 ushorts = 1 KB contiguous = one async16/wave.
// ---------------------------------------------------------------------------

// Kernel 0: transpose + bf16 + blockify.  in[512][C] fp32 (k-major), m = z*C+c.
//   Grid: (C/64, 8, batches); 256 threads.
__global__ __launch_bounds__(256) void blockify_kernel(
    const float* __restrict__ in, ushort_t* __restrict__ out, int C)
{
    __shared__ float t[64][65];
    const int k0 = blockIdx.y * 64, c0 = blockIdx.x * 64;
    const float* inb = in + (size_t)blockIdx.z * 512 * C;
    const int tid = threadIdx.x;
#pragma unroll
    for (int i = 0; i < 16; ++i) {
        int idx = tid + i * 256;
        int r = idx >> 6, c = idx & 63;
        t[r][c] = inb[(size_t)(k0 + r) * C + c0 + c];
    }
    __syncthreads();
    const size_t mbase = (size_t)blockIdx.z * C + c0;
    const int ml = tid & 63;
#pragma unroll
    for (int i = 0; i < 2; ++i) {
        int oct = (tid >> 6) + i * 4;          // k-octet 0..7
        size_t m = mbase + ml;
        int mt = (int)(m >> 7), mr = (int)(m & 127);
        int m16 = mr >> 4, col = mr & 15;
        int k = k0 + oct * 8;
        int it = k >> 5, q = (k >> 3) & 3;
        uint4 pk;
        pk.x = f2bf(t[oct * 8 + 0][ml]) | (f2bf(t[oct * 8 + 1][ml]) << 16);
        pk.y = f2bf(t[oct * 8 + 2][ml]) | (f2bf(t[oct * 8 + 3][ml]) << 16);
        pk.z = f2bf(t[oct * 8 + 4][ml]) | (f2bf(t[oct * 8 + 5][ml]) << 16);
        pk.w = f2bf(t[oct * 8 + 6][ml]) | (f2bf(t[oct * 8 + 7][ml]) << 16);
        size_t off = ((size_t)(mt * 16 + it) * 8 + m16) * 512 + (q * 16 + col) * 8;
        *(uint4*)&out[off] = pk;
    }
}

// ---------------------------------------------------------------------------
// Kernel 1: QKV GEMM (MFMA), BK=32, blocked contiguous staging, XCD swizzle.
//   v3: counted-vmcnt pipeline (T3+T4): prefetch depth 2, raw barriers,
//   vmcnt(4) at loop top keeps next tile's loads in flight (no drain).
//   v4: V written in pi-permuted row order (pi(tau)=h*32+(j>>2)*16+quad*4+
//   (j&3)) so attn's PV A-fragments need NO LDS round-trip.
//   Grid: (12, 128); 256 thr; 32 KB LDS.
// ---------------------------------------------------------------------------
__global__ __launch_bounds__(256) void qkv_gemm_kernel(
    const ushort_t* __restrict__ xtb, const ushort_t* __restrict__ WpTb,
    const float* __restrict__ bp,
    ushort_t* __restrict__ q_buf, ushort_t* __restrict__ kb,
    ushort_t* __restrict__ vb)
{
    __shared__ alignas(16) ushort_t Asub[2][8 * 512];   // 2 x 8 KB
    __shared__ alignas(16) ushort_t Bsub[2][8 * 512];   // 2 x 8 KB

    const int tid = threadIdx.x, w = tid >> 6, lane = tid & 63;
    const int quad = lane >> 4, col = lane & 15;
    const int wm = w >> 1, wn = w & 1;

    // XCD swizzle: all 12 n-tiles of one m-tile on one XCD
    const int lin = blockIdx.x + 12 * blockIdx.y;   // 0..1535
    const int xcd = lin & 7;
    const int rr  = lin >> 3;
    const int n0  = (rr % 12) * 128;
    const int m0  = ((rr / 12) * 8 + xcd) * 128;

    f32x4 acc[4][4];
#pragma unroll
    for (int i = 0; i < 4; ++i)
#pragma unroll
        for (int j = 0; j < 4; ++j) acc[i][j] = (f32x4){0.f, 0.f, 0.f, 0.f};

    const ushort_t* Ab = xtb  + (size_t)(m0 >> 7) * 65536 + (w * 2) * 512 + lane * 8;
    const ushort_t* Bb = WpTb + (size_t)(n0 >> 7) * 65536 + (w * 2) * 512 + lane * 8;

#define QKV_STAGE(buf, t)                                         \
    do {                                                          \
        async16(Ab + (t) * 4096,       &Asub[buf][(w * 2 + 0) * 512]); \
        async16(Ab + (t) * 4096 + 512, &Asub[buf][(w * 2 + 1) * 512]); \
        async16(Bb + (t) * 4096,       &Bsub[buf][(w * 2 + 0) * 512]); \
        async16(Bb + (t) * 4096 + 512, &Bsub[buf][(w * 2 + 1) * 512]); \
    } while (0)

    QKV_STAGE(0, 0);
    QKV_STAGE(1, 1);
    for (int it = 0; it < 16; ++it) {
        const int cur = it & 1;
        if (it < 15) { WAIT_VMCNT(4); } else { WAIT_VMCNT(0); }
        barrier_raw();                   // buf[cur] staged for all waves

        short8 af[4], bfr[4];
#pragma unroll
        for (int i = 0; i < 4; ++i) af[i]  = *(const short8*)&Asub[cur][(wm * 4 + i) * 512 + lane * 8];
#pragma unroll
        for (int j = 0; j < 4; ++j) bfr[j] = *(const short8*)&Bsub[cur][(wn * 4 + j) * 512 + lane * 8];
#pragma unroll
        for (int i = 0; i < 4; ++i)
#pragma unroll
            for (int j = 0; j < 4; ++j)
                acc[i][j] = __builtin_amdgcn_mfma_f32_16x16x32_bf16(af[i], bfr[j], acc[i][j], 0, 0, 0);

        if (it < 14) {
            barrier_raw();               // all waves done reading buf[cur]
            QKV_STAGE(cur, it + 2);
        }
    }
#undef QKV_STAGE

    // ---- epilogue: split q/k/v; q pre-scaled by QSCALE ----
    const int b = m0 >> 10, s0 = m0 & 1023;
    const size_t b8 = (size_t)b * HEADS;
#pragma unroll
    for (int j = 0; j < 4; ++j) {
        int nb = n0 + wn * 64 + j * 16;               // frag n base (wave-uniform)
        int h = nb / 192, rem = nb % 192;
        int type = rem >> 6, dbase = rem & 63;        // uniform per frag
        float bias = bp[nb + col];
        size_t bh = b8 + h;
        int d = dbase + col;
#pragma unroll
        for (int i = 0; i < 4; ++i) {
            int sb = s0 + wm * 64 + i * 16 + quad * 4;    // s for r=0
            f32x4 v = acc[i][j];
            if (type == 2) {
                // vb blocked + pi-permuted rows: slot tau for t=sb..sb+3 is
                // contiguous: tau&7 = ((sb>>4)&1)*4 + r, quad-slot = (sb>>2)&3
                unsigned lo = f2bf(v[0] + bias) | (f2bf(v[1] + bias) << 16);
                unsigned hi = f2bf(v[2] + bias) | (f2bf(v[3] + bias) << 16);
                uint2 pk; pk.x = lo; pk.y = hi;
                int itv = sb >> 6, sub = (d >> 4) * 2 + ((sb >> 5) & 1);
                size_t off = ((bh * 16 + itv) * 8 + sub) * 512
                           + (((sb >> 2) & 3) * 16 + (d & 15)) * 8
                           + ((sb >> 4) & 1) * 4;
                *(uint2*)&vb[off] = pk;
            } else if (type == 1) {
                // kb blocked: elem (bh,t,d): it=t>>6, sub=((t>>4)&3)*2+(d>>5)
#pragma unroll
                for (int r = 0; r < 4; ++r) {
                    int t = sb + r;
                    int itk = t >> 6, sub = ((t >> 4) & 3) * 2 + (d >> 5);
                    size_t off = ((bh * 16 + itk) * 8 + sub) * 512
                               + (((d >> 3) & 3) * 16 + (t & 15)) * 8 + (d & 7);
                    kb[off] = (ushort_t)f2bf(v[r] + bias);
                }
            } else {
#pragma unroll
                for (int r = 0; r < 4; ++r)
                    q_buf[(bh * SEQ + sb + r) * DHEAD + d] =
                        (ushort_t)f2bf((v[r] + bias) * QSCALE);
            }
        }
    }
}

// ---------------------------------------------------------------------------
// Kernel 2: MFMA flash attention; blocked contiguous K/V staging; dbuf;
//   unnormalized softmax via exp2 (q pre-scaled by log2e); S^T trick.
//   v4: ZERO P round-trip — V rows pi-permuted in vb so each lane's S^T
//   values ARE its PV A-fragment after exp2+pack (pure register op).
//   v5: group software pipeline — QK(g+1) MFMAs issued BEFORE exp2/pack/
//   PV(g) so matrix pipe and VALU overlap (they alternated before: Mfma 30%
//   + VALU 46% mutually exclusive).  Two alternating S buffers, statically
//   unrolled; V frags hoisted to regs; all setprio toggles removed (they
//   partitioned the scheduling region and blocked the interleave).
//   2 waves x 4 q-groups; __syncthreads dbuf; 32 KB LDS.
//   Grid: (bh=128, qtile=8); 128 threads.
// ---------------------------------------------------------------------------
__global__ __launch_bounds__(128) void attn_kernel(
    const ushort_t* __restrict__ q_buf, const ushort_t* __restrict__ kb,
    const ushort_t* __restrict__ vb, ushort_t* __restrict__ resb)
{
    __shared__ alignas(16) ushort_t Kf[2][8 * 512];   // ping-pong, 16 KB
    __shared__ alignas(16) ushort_t Vf[2][8 * 512];   // ping-pong, 16 KB

    const int tid  = threadIdx.x;
    const int w    = tid >> 6;            // 0..1
    const int lane = tid & 63;
    const int quad = lane >> 4;
    const int col  = lane & 15;

    const int bhid = blockIdx.x;          // 0..127
    const int b = bhid >> 3, h = bhid & 7;
    const int q0 = blockIdx.y * 128;
    const size_t bh = (size_t)b * HEADS + h;

    // Q B-frags for 4 groups (pre-scaled by QSCALE in qkv_gemm)
    // group g covers q rows q0 + w*64 + g*16 .. +15
    const ushort_t* qp = q_buf + ((bh * SEQ) + q0 + w * 64 + col) * DHEAD + quad * 8;
    short8 qf0[4], qf1[4];
#pragma unroll
    for (int g = 0; g < 4; ++g) {
        qf0[g] = *(const short8*)(qp + g * 16 * DHEAD);
        qf1[g] = *(const short8*)(qp + g * 16 * DHEAD + 32);
    }

    short8 ones;
#pragma unroll
    for (int i = 0; i < 8; ++i) ones[i] = (short)0x3F80;

    f32x4 O[4][4];
#pragma unroll
    for (int g = 0; g < 4; ++g)
#pragma unroll
        for (int i = 0; i < 4; ++i) O[g][i] = (f32x4){0.f, 0.f, 0.f, 0.f};
    f32x4 L[4];
#pragma unroll
    for (int g = 0; g < 4; ++g) L[g] = (f32x4){0.f, 0.f, 0.f, 0.f};

    // blocked contiguous staging pointers (wave w stages subs w*4+{0..3})
    const ushort_t* kaB = kb + (size_t)bh * 65536 + (w * 4) * 512 + lane * 8;
    const ushort_t* vaB = vb + (size_t)bh * 65536 + (w * 4) * 512 + lane * 8;

#define ATTN_STAGE(buf)                                            \
    do {                                                           \
        async16(kaB,        &Kf[buf][(w * 4 + 0) * 512]);          \
        async16(kaB + 512,  &Kf[buf][(w * 4 + 1) * 512]);          \
        async16(kaB + 1024, &Kf[buf][(w * 4 + 2) * 512]);          \
        async16(kaB + 1536, &Kf[buf][(w * 4 + 3) * 512]);          \
        async16(vaB,        &Vf[buf][(w * 4 + 0) * 512]);          \
        async16(vaB + 512,  &Vf[buf][(w * 4 + 1) * 512]);          \
        async16(vaB + 1024, &Vf[buf][(w * 4 + 2) * 512]);          \
        async16(vaB + 1536, &Vf[buf][(w * 4 + 3) * 512]);          \
        kaB += 4096;                                               \
        vaB += 4096;                                               \
    } while (0)

// S(g) = K.Q^T for group g (8 MFMA, matrix pipe)
#define QK_GRP(Sdst, g)                                                       \
    do {                                                                      \
        _Pragma("unroll")                                                     \
        for (int t16 = 0; t16 < 4; ++t16) {                                   \
            f32x4 a = (f32x4){0.f, 0.f, 0.f, 0.f};                            \
            a = __builtin_amdgcn_mfma_f32_16x16x32_bf16(kf[2 * t16 + 0], qf0[g], a, 0, 0, 0); \
            a = __builtin_amdgcn_mfma_f32_16x16x32_bf16(kf[2 * t16 + 1], qf1[g], a, 0, 0, 0); \
            Sdst[t16] = a;                                                    \
        }                                                                     \
    } while (0)

// exp2+pack (VALU) then PV+L (matrix) for group g — overlaps with the
// NEXT group's QK MFMAs already in flight.
#define CONSUME_GRP(g, S)                                                     \
    do {                                                                      \
        union { uint4 u; short8 s; } p0_, p1_;                                \
        p0_.u.x = pack_bf16_trunc(fast_exp2(S[0][0]), fast_exp2(S[0][1]));    \
        p0_.u.y = pack_bf16_trunc(fast_exp2(S[0][2]), fast_exp2(S[0][3]));    \
        p0_.u.z = pack_bf16_trunc(fast_exp2(S[1][0]), fast_exp2(S[1][1]));    \
        p0_.u.w = pack_bf16_trunc(fast_exp2(S[1][2]), fast_exp2(S[1][3]));    \
        p1_.u.x = pack_bf16_trunc(fast_exp2(S[2][0]), fast_exp2(S[2][1]));    \
        p1_.u.y = pack_bf16_trunc(fast_exp2(S[2][2]), fast_exp2(S[2][3]));    \
        p1_.u.z = pack_bf16_trunc(fast_exp2(S[3][0]), fast_exp2(S[3][1]));    \
        p1_.u.w = pack_bf16_trunc(fast_exp2(S[3][2]), fast_exp2(S[3][3]));    \
        const short8 pf0_ = p0_.s, pf1_ = p1_.s;                              \
        _Pragma("unroll")                                                     \
        for (int d16 = 0; d16 < 4; ++d16) {                                   \
            O[g][d16] = __builtin_amdgcn_mfma_f32_16x16x32_bf16(pf0_, vf[2 * d16 + 0], O[g][d16], 0, 0, 0); \
            O[g][d16] = __builtin_amdgcn_mfma_f32_16x16x32_bf16(pf1_, vf[2 * d16 + 1], O[g][d16], 0, 0, 0); \
        }                                                                     \
        L[g] = __builtin_amdgcn_mfma_f32_16x16x32_bf16(pf0_, ones, L[g], 0, 0, 0); \
        L[g] = __builtin_amdgcn_mfma_f32_16x16x32_bf16(pf1_, ones, L[g], 0, 0, 0); \
    } while (0)

    ATTN_STAGE(0);

    for (int it = 0; it < 16; ++it) {
        const int cur = it & 1;
        const ushort_t* kc = Kf[cur];
        const ushort_t* vc = Vf[cur];
        __syncthreads();   // buf[cur] staged; prior readers of buf[cur^1] done
        if (it < 15) ATTN_STAGE(cur ^ 1);

        // ---- K and V frags to regs once; shared by all 4 groups ----
        short8 kf[8], vf[8];
#pragma unroll
        for (int t16 = 0; t16 < 4; ++t16) {
            kf[2 * t16 + 0] = *(const short8*)&kc[(t16 * 2 + 0) * 512 + lane * 8];
            kf[2 * t16 + 1] = *(const short8*)&kc[(t16 * 2 + 1) * 512 + lane * 8];
        }
#pragma unroll
        for (int d16 = 0; d16 < 4; ++d16) {
            vf[2 * d16 + 0] = *(const short8*)&vc[(d16 * 2 + 0) * 512 + lane * 8];
            vf[2 * d16 + 1] = *(const short8*)&vc[(d16 * 2 + 1) * 512 + lane * 8];
        }

        // ---- group software pipeline: QK(g+1) in flight during consume(g) ----
        f32x4 Sa[4], Sb[4];
        QK_GRP(Sa, 0);
        QK_GRP(Sb, 1);
        CONSUME_GRP(0, Sa);
        QK_GRP(Sa, 2);
        CONSUME_GRP(1, Sb);
        QK_GRP(Sb, 3);
        CONSUME_GRP(2, Sa);
        CONSUME_GRP(3, Sb);
    }
#undef ATTN_STAGE
#undef QK_GRP
#undef CONSUME_GRP

    // ---- epilogue: O / L -> resb in out_gemm's blocked order ----
    const int mt = b * 8 + (q0 >> 7);
#pragma unroll
    for (int g = 0; g < 4; ++g) {
        const int m16 = w * 4 + g;
#pragma unroll
        for (int r = 0; r < 4; ++r) {
            float inv = 1.f / L[g][r];
            const int mcol = quad * 4 + r;
#pragma unroll
            for (int d16 = 0; d16 < 4; ++d16) {
                int itk = h * 2 + (d16 >> 1);
                int kq = (d16 & 1) * 2 + (col >> 3);
                size_t off = ((size_t)(mt * 16 + itk) * 8 + m16) * 512
                           + (kq * 16 + mcol) * 8 + (col & 7);
                resb[off] = (ushort_t)f2bf(O[g][d16][r] * inv);
            }
        }
    }
}

// ---------------------------------------------------------------------------
// Kernel 3: out GEMM (MFMA), BK=32, blocked staging, XCD swizzle.
//   v3: counted-vmcnt pipeline (same as qkv).  Grid: (4, 128); 32 KB LDS.
// ---------------------------------------------------------------------------
__global__ __launch_bounds__(256) void out_gemm_kernel(
    const ushort_t* __restrict__ resb, const ushort_t* __restrict__ WoTb,
    const float* __restrict__ bo, const float* __restrict__ x,
    float* __restrict__ out)
{
    __shared__ alignas(16) ushort_t Asub[2][8 * 512];
    __shared__ alignas(16) ushort_t Bsub[2][8 * 512];

    const int tid = threadIdx.x, w = tid >> 6, lane = tid & 63;
    const int quad = lane >> 4, col = lane & 15;
    const int wm = w >> 1, wn = w & 1;

    const int lin = blockIdx.x + 4 * blockIdx.y;    // 0..511
    const int xcd = lin & 7;
    const int rr  = lin >> 3;
    const int n0  = (rr & 3) * 128;
    const int m0  = ((rr >> 2) * 8 + xcd) * 128;

    f32x4 acc[4][4];
#pragma unroll
    for (int i = 0; i < 4; ++i)
#pragma unroll
        for (int j = 0; j < 4; ++j) acc[i][j] = (f32x4){0.f, 0.f, 0.f, 0.f};

    const ushort_t* Ab = resb + (size_t)(m0 >> 7) * 65536 + (w * 2) * 512 + lane * 8;
    const ushort_t* Bb = WoTb + (size_t)(n0 >> 7) * 65536 + (w * 2) * 512 + lane * 8;

#define OUT_STAGE(buf, t)                                         \
    do {                                                          \
        async16(Ab + (t) * 4096,       &Asub[buf][(w * 2 + 0) * 512]); \
        async16(Ab + (t) * 4096 + 512, &Asub[buf][(w * 2 + 1) * 512]); \
        async16(Bb + (t) * 4096,       &Bsub[buf][(w * 2 + 0) * 512]); \
        async16(Bb + (t) * 4096 + 512, &Bsub[buf][(w * 2 + 1) * 512]); \
    } while (0)

    OUT_STAGE(0, 0);
    OUT_STAGE(1, 1);
    for (int it = 0; it < 16; ++it) {
        const int cur = it & 1;
        if (it < 15) { WAIT_VMCNT(4); } else { WAIT_VMCNT(0); }
        barrier_raw();

        short8 af[4], bfr[4];
#pragma unroll
        for (int i = 0; i < 4; ++i) af[i]  = *(const short8*)&Asub[cur][(wm * 4 + i) * 512 + lane * 8];
#pragma unroll
        for (int j = 0; j < 4; ++j) bfr[j] = *(const short8*)&Bsub[cur][(wn * 4 + j) * 512 + lane * 8];
#pragma unroll
        for (int i = 0; i < 4; ++i)
#pragma unroll
            for (int j = 0; j < 4; ++j)
                acc[i][j] = __builtin_amdgcn_mfma_f32_16x16x32_bf16(af[i], bfr[j], acc[i][j], 0, 0, 0);

        if (it < 14) {
            barrier_raw();
            OUT_STAGE(cur, it + 2);
        }
    }
#undef OUT_STAGE

    const int b = m0 >> 10, s0 = m0 & 1023;
#pragma unroll
    for (int j = 0; j < 4; ++j) {
        int n = n0 + wn * 64 + j * 16 + col;
        float bias = bo[n];
#pragma unroll
        for (int i = 0; i < 4; ++i) {
            int sb = s0 + wm * 64 + i * 16 + quad * 4;
            size_t o = ((size_t)b * CDIM + n) * SEQ + sb;
            float4 xr = *(const float4*)&x[o];
            f32x4 v = acc[i][j];
            float4 ov;
            ov.x = v[0] + bias + xr.x;
            ov.y = v[1] + bias + xr.y;
            ov.z = v[2] + bias + xr.z;
            ov.w = v[3] + bias + xr.w;
            *(float4*)&out[o] = ov;
        }
    }
}

// ---------------------------------------------------------------------------
extern "C" void kernel_launch(void* const* d_in, const int* in_sizes, int n_in,
                              void* d_out, int out_size, void* d_ws, size_t ws_size,
                              hipStream_t stream) {
    const float* x  = (const float*)d_in[0];   // (16, 512, 32, 32) fp32
    const float* Wp = (const float*)d_in[1];   // (512, 1536) fp32
    const float* bp = (const float*)d_in[2];   // (1536,) fp32
    const float* Wo = (const float*)d_in[3];   // (512, 512) fp32
    const float* bo = (const float*)d_in[4];   // (512,) fp32
    float* out = (float*)d_out;                // (16, 512, 32, 32) fp32

    // ws layout (ushort units), ~86 MB
    ushort_t* xtb   = (ushort_t*)d_ws;               // blocked [mt][it][sub][lane][8]
    ushort_t* WpTb  = xtb   + (size_t)8388608;
    ushort_t* WoTb  = WpTb  + (size_t)786432;
    ushort_t* q_buf = WoTb  + (size_t)262144;        // row-major [bh][s][d]
    ushort_t* kb    = q_buf + (size_t)8388608;       // attn-blocked
    ushort_t* vb    = kb    + (size_t)8388608;       // attn-blocked, pi-permuted rows
    ushort_t* resb  = vb    + (size_t)8388608;       // out_gemm-blocked

    blockify_kernel<<<dim3(16, 8, 16), 256, 0, stream>>>(x,  xtb,  1024);
    blockify_kernel<<<dim3(24, 8, 1),  256, 0, stream>>>(Wp, WpTb, 1536);
    blockify_kernel<<<dim3(8, 8, 1),   256, 0, stream>>>(Wo, WoTb, 512);
    qkv_gemm_kernel<<<dim3(12, 128), 256, 0, stream>>>(xtb, WpTb, bp, q_buf, kb, vb);
    attn_kernel<<<dim3(128, 8), 128, 0, stream>>>(q_buf, kb, vb, resb);
    out_gemm_kernel<<<dim3(4, 128), 256, 0, stream>>>(resb, WoTb, bo, x, out);
}

// Round 6
// 199.237 us; speedup vs baseline: 1.0270x; 1.0270x over previous
//
#include <hip/hip_runtime.h>
#include <hip/hip_bf16.h>

#define BATCH 16
#define CDIM  512
#define SEQ   1024
#define HEADS 8
#define DHEAD 64
#define N3    1536      // 3 * HEADS * DHEAD
// q pre-scale: dk^-0.5 * log2(e), so attn uses exp2 directly (softmax-invariant)
#define QSCALE 0.18033688011112042f

typedef unsigned short ushort_t;
typedef __attribute__((ext_vector_type(8))) short short8;   // 8 bf16 (4 VGPRs)
typedef __attribute__((ext_vector_type(4))) float f32x4;

// fp32 -> bf16 bits, round-to-nearest-even
__device__ __forceinline__ unsigned f2bf(float f) {
    unsigned u = __float_as_uint(f);
    u += 0x7fffu + ((u >> 16) & 1u);
    return u >> 16;
}
// 2^x via v_exp_f32 (quarter-rate transcendental; inputs are normal-range)
__device__ __forceinline__ float fast_exp2(float x) {
    float r;
    asm("v_exp_f32 %0, %1" : "=v"(r) : "v"(x));
    return r;
}
// pack trunc-bf16(lo), trunc-bf16(hi) -> one u32 via v_perm_b32 (1 VALU op)
__device__ __forceinline__ unsigned pack_bf16_trunc(float lo, float hi) {
    return __builtin_amdgcn_perm(__float_as_uint(hi), __float_as_uint(lo), 0x07060302u);
}
// async global->LDS, 16B/lane; per-lane ptr pre-offset by lane*16B so each
// wave covers 1 KB CONTIGUOUS global memory (one transaction, not 64).
__device__ __forceinline__ void async16(const void* g, void* l) {
    __builtin_amdgcn_global_load_lds(
        (const __attribute__((address_space(1))) unsigned int*)g,
        (__attribute__((address_space(3))) unsigned int*)l, 16, 0, 0);
}
// raw barrier (no vmcnt drain) fenced against compiler reordering
__device__ __forceinline__ void barrier_raw() {
    __builtin_amdgcn_sched_barrier(0);
    __builtin_amdgcn_s_barrier();
    __builtin_amdgcn_sched_barrier(0);
}
// counted vmcnt wait: leaves newest N loads in flight across the barrier (T4)
#define WAIT_VMCNT(n) asm volatile("s_waitcnt vmcnt(" #n ")" ::: "memory")

// ---------------------------------------------------------------------------
// Blocked fragment-order layout for GEMM staging (all staged operands):
//   element (m, k):  mt=m>>7, mr=m&127, m16=mr>>4, col=mr&15,
//                    it=k>>5, q=(k>>3)&3, j=k&7
//   off = ((mt*16+it)*8 + m16)*512 + (q*16+col)*8 + j
// One (mt,it,m16) chunk = 512 ushorts = 1 KB contiguous = one async16/wave.
// ---------------------------------------------------------------------------

// Kernel 0: transpose + bf16 + blockify.  in[512][C] fp32 (k-major), m = z*C+c.
//   Grid: (C/64, 8, batches); 256 threads.
__global__ __launch_bounds__(256) void blockify_kernel(
    const float* __restrict__ in, ushort_t* __restrict__ out, int C)
{
    __shared__ float t[64][65];
    const int k0 = blockIdx.y * 64, c0 = blockIdx.x * 64;
    const float* inb = in + (size_t)blockIdx.z * 512 * C;
    const int tid = threadIdx.x;
#pragma unroll
    for (int i = 0; i < 16; ++i) {
        int idx = tid + i * 256;
        int r = idx >> 6, c = idx & 63;
        t[r][c] = inb[(size_t)(k0 + r) * C + c0 + c];
    }
    __syncthreads();
    const size_t mbase = (size_t)blockIdx.z * C + c0;
    const int ml = tid & 63;
#pragma unroll
    for (int i = 0; i < 2; ++i) {
        int oct = (tid >> 6) + i * 4;          // k-octet 0..7
        size_t m = mbase + ml;
        int mt = (int)(m >> 7), mr = (int)(m & 127);
        int m16 = mr >> 4, col = mr & 15;
        int k = k0 + oct * 8;
        int it = k >> 5, q = (k >> 3) & 3;
        uint4 pk;
        pk.x = f2bf(t[oct * 8 + 0][ml]) | (f2bf(t[oct * 8 + 1][ml]) << 16);
        pk.y = f2bf(t[oct * 8 + 2][ml]) | (f2bf(t[oct * 8 + 3][ml]) << 16);
        pk.z = f2bf(t[oct * 8 + 4][ml]) | (f2bf(t[oct * 8 + 5][ml]) << 16);
        pk.w = f2bf(t[oct * 8 + 6][ml]) | (f2bf(t[oct * 8 + 7][ml]) << 16);
        size_t off = ((size_t)(mt * 16 + it) * 8 + m16) * 512 + (q * 16 + col) * 8;
        *(uint4*)&out[off] = pk;
    }
}

// ---------------------------------------------------------------------------
// Kernel 1: QKV GEMM (MFMA), BK=32, blocked contiguous staging, XCD swizzle.
//   v3: counted-vmcnt pipeline (T3+T4): prefetch depth 2, raw barriers,
//   vmcnt(4) at loop top keeps next tile's loads in flight (no drain).
//   v4: V written in pi-permuted row order so attn's PV A-fragments need
//   NO LDS round-trip.  Grid: (12, 128); 256 thr; 32 KB LDS.
// ---------------------------------------------------------------------------
__global__ __launch_bounds__(256) void qkv_gemm_kernel(
    const ushort_t* __restrict__ xtb, const ushort_t* __restrict__ WpTb,
    const float* __restrict__ bp,
    ushort_t* __restrict__ q_buf, ushort_t* __restrict__ kb,
    ushort_t* __restrict__ vb)
{
    __shared__ alignas(16) ushort_t Asub[2][8 * 512];   // 2 x 8 KB
    __shared__ alignas(16) ushort_t Bsub[2][8 * 512];   // 2 x 8 KB

    const int tid = threadIdx.x, w = tid >> 6, lane = tid & 63;
    const int quad = lane >> 4, col = lane & 15;
    const int wm = w >> 1, wn = w & 1;

    // XCD swizzle: all 12 n-tiles of one m-tile on one XCD
    const int lin = blockIdx.x + 12 * blockIdx.y;   // 0..1535
    const int xcd = lin & 7;
    const int rr  = lin >> 3;
    const int n0  = (rr % 12) * 128;
    const int m0  = ((rr / 12) * 8 + xcd) * 128;

    f32x4 acc[4][4];
#pragma unroll
    for (int i = 0; i < 4; ++i)
#pragma unroll
        for (int j = 0; j < 4; ++j) acc[i][j] = (f32x4){0.f, 0.f, 0.f, 0.f};

    const ushort_t* Ab = xtb  + (size_t)(m0 >> 7) * 65536 + (w * 2) * 512 + lane * 8;
    const ushort_t* Bb = WpTb + (size_t)(n0 >> 7) * 65536 + (w * 2) * 512 + lane * 8;

#define QKV_STAGE(buf, t)                                         \
    do {                                                          \
        async16(Ab + (t) * 4096,       &Asub[buf][(w * 2 + 0) * 512]); \
        async16(Ab + (t) * 4096 + 512, &Asub[buf][(w * 2 + 1) * 512]); \
        async16(Bb + (t) * 4096,       &Bsub[buf][(w * 2 + 0) * 512]); \
        async16(Bb + (t) * 4096 + 512, &Bsub[buf][(w * 2 + 1) * 512]); \
    } while (0)

    QKV_STAGE(0, 0);
    QKV_STAGE(1, 1);
    for (int it = 0; it < 16; ++it) {
        const int cur = it & 1;
        if (it < 15) { WAIT_VMCNT(4); } else { WAIT_VMCNT(0); }
        barrier_raw();                   // buf[cur] staged for all waves

        short8 af[4], bfr[4];
#pragma unroll
        for (int i = 0; i < 4; ++i) af[i]  = *(const short8*)&Asub[cur][(wm * 4 + i) * 512 + lane * 8];
#pragma unroll
        for (int j = 0; j < 4; ++j) bfr[j] = *(const short8*)&Bsub[cur][(wn * 4 + j) * 512 + lane * 8];
#pragma unroll
        for (int i = 0; i < 4; ++i)
#pragma unroll
            for (int j = 0; j < 4; ++j)
                acc[i][j] = __builtin_amdgcn_mfma_f32_16x16x32_bf16(af[i], bfr[j], acc[i][j], 0, 0, 0);

        if (it < 14) {
            barrier_raw();               // all waves done reading buf[cur]
            QKV_STAGE(cur, it + 2);
        }
    }
#undef QKV_STAGE

    // ---- epilogue: split q/k/v; q pre-scaled by QSCALE ----
    const int b = m0 >> 10, s0 = m0 & 1023;
    const size_t b8 = (size_t)b * HEADS;
#pragma unroll
    for (int j = 0; j < 4; ++j) {
        int nb = n0 + wn * 64 + j * 16;               // frag n base (wave-uniform)
        int h = nb / 192, rem = nb % 192;
        int type = rem >> 6, dbase = rem & 63;        // uniform per frag
        float bias = bp[nb + col];
        size_t bh = b8 + h;
        int d = dbase + col;
#pragma unroll
        for (int i = 0; i < 4; ++i) {
            int sb = s0 + wm * 64 + i * 16 + quad * 4;    // s for r=0
            f32x4 v = acc[i][j];
            if (type == 2) {
                // vb blocked + pi-permuted rows: slot tau for t=sb..sb+3 is
                // contiguous: tau&7 = ((sb>>4)&1)*4 + r, quad-slot = (sb>>2)&3
                unsigned lo = f2bf(v[0] + bias) | (f2bf(v[1] + bias) << 16);
                unsigned hi = f2bf(v[2] + bias) | (f2bf(v[3] + bias) << 16);
                uint2 pk; pk.x = lo; pk.y = hi;
                int itv = sb >> 6, sub = (d >> 4) * 2 + ((sb >> 5) & 1);
                size_t off = ((bh * 16 + itv) * 8 + sub) * 512
                           + (((sb >> 2) & 3) * 16 + (d & 15)) * 8
                           + ((sb >> 4) & 1) * 4;
                *(uint2*)&vb[off] = pk;
            } else if (type == 1) {
                // kb blocked: elem (bh,t,d): it=t>>6, sub=((t>>4)&3)*2+(d>>5)
#pragma unroll
                for (int r = 0; r < 4; ++r) {
                    int t = sb + r;
                    int itk = t >> 6, sub = ((t >> 4) & 3) * 2 + (d >> 5);
                    size_t off = ((bh * 16 + itk) * 8 + sub) * 512
                               + (((d >> 3) & 3) * 16 + (t & 15)) * 8 + (d & 7);
                    kb[off] = (ushort_t)f2bf(v[r] + bias);
                }
            } else {
#pragma unroll
                for (int r = 0; r < 4; ++r)
                    q_buf[(bh * SEQ + sb + r) * DHEAD + d] =
                        (ushort_t)f2bf((v[r] + bias) * QSCALE);
            }
        }
    }
}

// ---------------------------------------------------------------------------
// Kernel 2: MFMA flash attention; blocked contiguous K/V staging; dbuf;
//   unnormalized softmax via exp2 (q pre-scaled by log2e); S^T trick.
//   v4: ZERO P round-trip — V rows pi-permuted in vb so each lane's S^T
//   values ARE its PV A-fragment after exp2+pack (pure register op).
//   v6: 4 waves x 2 q-groups (256 thr) — doubles waves/SIMD to 4 for
//   latency hiding (v4's 2 waves/SIMD had nothing saturated: Mfma 30%,
//   VALU 46%, occ 18% = latency-bound).  Per-wave VGPR drops (O/L/qf
//   halved) so the extra waves fit.  v5's manual pipelining reverted
//   (regressed: +36 VGPR, occ 10%, L2 reuse lost).
//   32 KB LDS -> 4 blocks/CU, grid 1024 = exact fit; grid x=bh keeps all
//   q-tiles of one bh on one XCD for K/V L2 reuse.
//   Grid: (bh=128, qtile=8); 256 threads.
// ---------------------------------------------------------------------------
__global__ __launch_bounds__(256) void attn_kernel(
    const ushort_t* __restrict__ q_buf, const ushort_t* __restrict__ kb,
    const ushort_t* __restrict__ vb, ushort_t* __restrict__ resb)
{
    __shared__ alignas(16) ushort_t Kf[2][8 * 512];   // ping-pong, 16 KB
    __shared__ alignas(16) ushort_t Vf[2][8 * 512];   // ping-pong, 16 KB

    const int tid  = threadIdx.x;
    const int w    = tid >> 6;            // 0..3
    const int lane = tid & 63;
    const int quad = lane >> 4;
    const int col  = lane & 15;

    const int bhid = blockIdx.x;          // 0..127
    const int b = bhid >> 3, h = bhid & 7;
    const int q0 = blockIdx.y * 128;
    const size_t bh = (size_t)b * HEADS + h;

    // Q B-frags for 2 groups (pre-scaled by QSCALE in qkv_gemm)
    // group g covers q rows q0 + w*32 + g*16 .. +15
    const ushort_t* qp = q_buf + ((bh * SEQ) + q0 + w * 32 + col) * DHEAD + quad * 8;
    short8 qf0[2], qf1[2];
#pragma unroll
    for (int g = 0; g < 2; ++g) {
        qf0[g] = *(const short8*)(qp + g * 16 * DHEAD);
        qf1[g] = *(const short8*)(qp + g * 16 * DHEAD + 32);
    }

    short8 ones;
#pragma unroll
    for (int i = 0; i < 8; ++i) ones[i] = (short)0x3F80;

    f32x4 O[2][4];
#pragma unroll
    for (int g = 0; g < 2; ++g)
#pragma unroll
        for (int i = 0; i < 4; ++i) O[g][i] = (f32x4){0.f, 0.f, 0.f, 0.f};
    f32x4 L[2];
#pragma unroll
    for (int g = 0; g < 2; ++g) L[g] = (f32x4){0.f, 0.f, 0.f, 0.f};

    // blocked contiguous staging pointers (wave w stages subs w*2+{0,1})
    const ushort_t* kaB = kb + (size_t)bh * 65536 + (w * 2) * 512 + lane * 8;
    const ushort_t* vaB = vb + (size_t)bh * 65536 + (w * 2) * 512 + lane * 8;

#define ATTN_STAGE(buf)                                            \
    do {                                                           \
        async16(kaB,        &Kf[buf][(w * 2 + 0) * 512]);          \
        async16(kaB + 512,  &Kf[buf][(w * 2 + 1) * 512]);          \
        async16(vaB,        &Vf[buf][(w * 2 + 0) * 512]);          \
        async16(vaB + 512,  &Vf[buf][(w * 2 + 1) * 512]);          \
        kaB += 4096;                                               \
        vaB += 4096;                                               \
    } while (0)

    ATTN_STAGE(0);

    for (int it = 0; it < 16; ++it) {
        const int cur = it & 1;
        const ushort_t* kc = Kf[cur];
        const ushort_t* vc = Vf[cur];
        __syncthreads();   // buf[cur] staged; prior readers of buf[cur^1] done
        if (it < 15) ATTN_STAGE(cur ^ 1);

        // ---- K frags to regs once; shared by both groups ----
        short8 kf[8];
#pragma unroll
        for (int t16 = 0; t16 < 4; ++t16) {
            kf[2 * t16 + 0] = *(const short8*)&kc[(t16 * 2 + 0) * 512 + lane * 8];
            kf[2 * t16 + 1] = *(const short8*)&kc[(t16 * 2 + 1) * 512 + lane * 8];
        }

        // ---- per group: S^T = K Q^T; P fragments built IN REGISTERS ----
        // lane holds S^T[t=t16*16+quad*4+r][q=col]; under vb's pi-permutation
        // pf[0] = bf16(exp2(S[0][0..3]), exp2(S[1][0..3])), pf[1] = t16 2,3.
        short8 pf[2][2];
#pragma unroll
        for (int g = 0; g < 2; ++g) {
            f32x4 S[4];
            __builtin_amdgcn_s_setprio(1);
#pragma unroll
            for (int t16 = 0; t16 < 4; ++t16) {
                f32x4 a = (f32x4){0.f, 0.f, 0.f, 0.f};
                a = __builtin_amdgcn_mfma_f32_16x16x32_bf16(kf[2 * t16 + 0], qf0[g], a, 0, 0, 0);
                a = __builtin_amdgcn_mfma_f32_16x16x32_bf16(kf[2 * t16 + 1], qf1[g], a, 0, 0, 0);
                S[t16] = a;
            }
            __builtin_amdgcn_s_setprio(0);
            union { uint4 u; short8 s; } p0, p1;
            p0.u.x = pack_bf16_trunc(fast_exp2(S[0][0]), fast_exp2(S[0][1]));
            p0.u.y = pack_bf16_trunc(fast_exp2(S[0][2]), fast_exp2(S[0][3]));
            p0.u.z = pack_bf16_trunc(fast_exp2(S[1][0]), fast_exp2(S[1][1]));
            p0.u.w = pack_bf16_trunc(fast_exp2(S[1][2]), fast_exp2(S[1][3]));
            p1.u.x = pack_bf16_trunc(fast_exp2(S[2][0]), fast_exp2(S[2][1]));
            p1.u.y = pack_bf16_trunc(fast_exp2(S[2][2]), fast_exp2(S[2][3]));
            p1.u.z = pack_bf16_trunc(fast_exp2(S[3][0]), fast_exp2(S[3][1]));
            p1.u.w = pack_bf16_trunc(fast_exp2(S[3][2]), fast_exp2(S[3][3]));
            pf[g][0] = p0.s;
            pf[g][1] = p1.s;
        }

        // ---- O += P V ; V frags read once/d16, shared by both groups ----
#pragma unroll
        for (int d16 = 0; d16 < 4; ++d16) {
            const short8 v0 = *(const short8*)&vc[(d16 * 2 + 0) * 512 + lane * 8];
            const short8 v1 = *(const short8*)&vc[(d16 * 2 + 1) * 512 + lane * 8];
            __builtin_amdgcn_s_setprio(1);
#pragma unroll
            for (int g = 0; g < 2; ++g) {
                O[g][d16] = __builtin_amdgcn_mfma_f32_16x16x32_bf16(pf[g][0], v0, O[g][d16], 0, 0, 0);
                O[g][d16] = __builtin_amdgcn_mfma_f32_16x16x32_bf16(pf[g][1], v1, O[g][d16], 0, 0, 0);
            }
            __builtin_amdgcn_s_setprio(0);
        }
#pragma unroll
        for (int g = 0; g < 2; ++g) {
            L[g] = __builtin_amdgcn_mfma_f32_16x16x32_bf16(pf[g][0], ones, L[g], 0, 0, 0);
            L[g] = __builtin_amdgcn_mfma_f32_16x16x32_bf16(pf[g][1], ones, L[g], 0, 0, 0);
        }
    }
#undef ATTN_STAGE

    // ---- epilogue: O / L -> resb in out_gemm's blocked order ----
    const int mt = b * 8 + (q0 >> 7);
#pragma unroll
    for (int g = 0; g < 2; ++g) {
        const int m16 = w * 2 + g;
#pragma unroll
        for (int r = 0; r < 4; ++r) {
            float inv = 1.f / L[g][r];
            const int mcol = quad * 4 + r;
#pragma unroll
            for (int d16 = 0; d16 < 4; ++d16) {
                int itk = h * 2 + (d16 >> 1);
                int kq = (d16 & 1) * 2 + (col >> 3);
                size_t off = ((size_t)(mt * 16 + itk) * 8 + m16) * 512
                           + (kq * 16 + mcol) * 8 + (col & 7);
                resb[off] = (ushort_t)f2bf(O[g][d16][r] * inv);
            }
        }
    }
}

// ---------------------------------------------------------------------------
// Kernel 3: out GEMM (MFMA), BK=32, blocked staging, XCD swizzle.
//   v3: counted-vmcnt pipeline (same as qkv).  Grid: (4, 128); 32 KB LDS.
// ---------------------------------------------------------------------------
__global__ __launch_bounds__(256) void out_gemm_kernel(
    const ushort_t* __restrict__ resb, const ushort_t* __restrict__ WoTb,
    const float* __restrict__ bo, const float* __restrict__ x,
    float* __restrict__ out)
{
    __shared__ alignas(16) ushort_t Asub[2][8 * 512];
    __shared__ alignas(16) ushort_t Bsub[2][8 * 512];

    const int tid = threadIdx.x, w = tid >> 6, lane = tid & 63;
    const int quad = lane >> 4, col = lane & 15;
    const int wm = w >> 1, wn = w & 1;

    const int lin = blockIdx.x + 4 * blockIdx.y;    // 0..511
    const int xcd = lin & 7;
    const int rr  = lin >> 3;
    const int n0  = (rr & 3) * 128;
    const int m0  = ((rr >> 2) * 8 + xcd) * 128;

    f32x4 acc[4][4];
#pragma unroll
    for (int i = 0; i < 4; ++i)
#pragma unroll
        for (int j = 0; j < 4; ++j) acc[i][j] = (f32x4){0.f, 0.f, 0.f, 0.f};

    const ushort_t* Ab = resb + (size_t)(m0 >> 7) * 65536 + (w * 2) * 512 + lane * 8;
    const ushort_t* Bb = WoTb + (size_t)(n0 >> 7) * 65536 + (w * 2) * 512 + lane * 8;

#define OUT_STAGE(buf, t)                                         \
    do {                                                          \
        async16(Ab + (t) * 4096,       &Asub[buf][(w * 2 + 0) * 512]); \
        async16(Ab + (t) * 4096 + 512, &Asub[buf][(w * 2 + 1) * 512]); \
        async16(Bb + (t) * 4096,       &Bsub[buf][(w * 2 + 0) * 512]); \
        async16(Bb + (t) * 4096 + 512, &Bsub[buf][(w * 2 + 1) * 512]); \
    } while (0)

    OUT_STAGE(0, 0);
    OUT_STAGE(1, 1);
    for (int it = 0; it < 16; ++it) {
        const int cur = it & 1;
        if (it < 15) { WAIT_VMCNT(4); } else { WAIT_VMCNT(0); }
        barrier_raw();

        short8 af[4], bfr[4];
#pragma unroll
        for (int i = 0; i < 4; ++i) af[i]  = *(const short8*)&Asub[cur][(wm * 4 + i) * 512 + lane * 8];
#pragma unroll
        for (int j = 0; j < 4; ++j) bfr[j] = *(const short8*)&Bsub[cur][(wn * 4 + j) * 512 + lane * 8];
#pragma unroll
        for (int i = 0; i < 4; ++i)
#pragma unroll
            for (int j = 0; j < 4; ++j)
                acc[i][j] = __builtin_amdgcn_mfma_f32_16x16x32_bf16(af[i], bfr[j], acc[i][j], 0, 0, 0);

        if (it < 14) {
            barrier_raw();
            OUT_STAGE(cur, it + 2);
        }
    }
#undef OUT_STAGE

    const int b = m0 >> 10, s0 = m0 & 1023;
#pragma unroll
    for (int j = 0; j < 4; ++j) {
        int n = n0 + wn * 64 + j * 16 + col;
        float bias = bo[n];
#pragma unroll
        for (int i = 0; i < 4; ++i) {
            int sb = s0 + wm * 64 + i * 16 + quad * 4;
            size_t o = ((size_t)b * CDIM + n) * SEQ + sb;
            float4 xr = *(const float4*)&x[o];
            f32x4 v = acc[i][j];
            float4 ov;
            ov.x = v[0] + bias + xr.x;
            ov.y = v[1] + bias + xr.y;
            ov.z = v[2] + bias + xr.z;
            ov.w = v[3] + bias + xr.w;
            *(float4*)&out[o] = ov;
        }
    }
}

// ---------------------------------------------------------------------------
extern "C" void kernel_launch(void* const* d_in, const int* in_sizes, int n_in,
                              void* d_out, int out_size, void* d_ws, size_t ws_size,
                              hipStream_t stream) {
    const float* x  = (const float*)d_in[0];   // (16, 512, 32, 32) fp32
    const float* Wp = (const float*)d_in[1];   // (512, 1536) fp32
    const float* bp = (const float*)d_in[2];   // (1536,) fp32
    const float* Wo = (const float*)d_in[3];   // (512, 512) fp32
    const float* bo = (const float*)d_in[4];   // (512,) fp32
    float* out = (float*)d_out;                // (16, 512, 32, 32) fp32

    // ws layout (ushort units), ~86 MB
    ushort_t* xtb   = (ushort_t*)d_ws;               // blocked [mt][it][sub][lane][8]
    ushort_t* WpTb  = xtb   + (size_t)8388608;
    ushort_t* WoTb  = WpTb  + (size_t)786432;
    ushort_t* q_buf = WoTb  + (size_t)262144;        // row-major [bh][s][d]
    ushort_t* kb    = q_buf + (size_t)8388608;       // attn-blocked
    ushort_t* vb    = kb    + (size_t)8388608;       // attn-blocked, pi-permuted rows
    ushort_t* resb  = vb    + (size_t)8388608;       // out_gemm-blocked

    blockify_kernel<<<dim3(16, 8, 16), 256, 0, stream>>>(x,  xtb,  1024);
    blockify_kernel<<<dim3(24, 8, 1),  256, 0, stream>>>(Wp, WpTb, 1536);
    blockify_kernel<<<dim3(8, 8, 1),   256, 0, stream>>>(Wo, WoTb, 512);
    qkv_gemm_kernel<<<dim3(12, 128), 256, 0, stream>>>(xtb, WpTb, bp, q_buf, kb, vb);
    attn_kernel<<<dim3(128, 8), 256, 0, stream>>>(q_buf, kb, vb, resb);
    out_gemm_kernel<<<dim3(4, 128), 256, 0, stream>>>(resb, WoTb, bo, x, out);
}

// Round 7
// 187.640 us; speedup vs baseline: 1.0905x; 1.0618x over previous
//
#include <hip/hip_runtime.h>
#include <hip/hip_bf16.h>

#define BATCH 16
#define CDIM  512
#define SEQ   1024
#define HEADS 8
#define DHEAD 64
#define N3    1536      // 3 * HEADS * DHEAD
// q pre-scale: dk^-0.5 * log2(e), so attn uses exp2 directly (softmax-invariant)
#define QSCALE 0.18033688011112042f

typedef unsigned short ushort_t;
typedef __attribute__((ext_vector_type(8))) short short8;   // 8 bf16 (4 VGPRs)
typedef __attribute__((ext_vector_type(4))) float f32x4;

// fp32 -> bf16 bits, round-to-nearest-even
__device__ __forceinline__ unsigned f2bf(float f) {
    unsigned u = __float_as_uint(f);
    u += 0x7fffu + ((u >> 16) & 1u);
    return u >> 16;
}
// 2^x via v_exp_f32 (quarter-rate transcendental; inputs are normal-range)
__device__ __forceinline__ float fast_exp2(float x) {
    float r;
    asm("v_exp_f32 %0, %1" : "=v"(r) : "v"(x));
    return r;
}
// pack trunc-bf16(lo), trunc-bf16(hi) -> one u32 via v_perm_b32 (1 VALU op)
__device__ __forceinline__ unsigned pack_bf16_trunc(float lo, float hi) {
    return __builtin_amdgcn_perm(__float_as_uint(hi), __float_as_uint(lo), 0x07060302u);
}
// async global->LDS, 16B/lane; per-lane ptr pre-offset by lane*16B so each
// wave covers 1 KB CONTIGUOUS global memory (one transaction, not 64).
__device__ __forceinline__ void async16(const void* g, void* l) {
    __builtin_amdgcn_global_load_lds(
        (const __attribute__((address_space(1))) unsigned int*)g,
        (__attribute__((address_space(3))) unsigned int*)l, 16, 0, 0);
}
// raw barrier (no vmcnt drain) fenced against compiler reordering
__device__ __forceinline__ void barrier_raw() {
    __builtin_amdgcn_sched_barrier(0);
    __builtin_amdgcn_s_barrier();
    __builtin_amdgcn_sched_barrier(0);
}
// counted vmcnt wait: leaves newest N loads in flight across the barrier (T4)
#define WAIT_VMCNT(n) asm volatile("s_waitcnt vmcnt(" #n ")" ::: "memory")

// ---------------------------------------------------------------------------
// Blocked fragment-order layout for GEMM staging (all staged operands):
//   element (m, k):  mt=m>>7, mr=m&127, m16=mr>>4, col=mr&15,
//                    it=k>>5, q=(k>>3)&3, j=k&7
//   off = ((mt*16+it)*8 + m16)*512 + (q*16+col)*8 + j
// One (mt,it,m16) chunk = 512 ushorts = 1 KB contiguous = one async16/wave.
// ---------------------------------------------------------------------------

// Kernel 0: transpose + bf16 + blockify.  in[512][C] fp32 (k-major), m = z*C+c.
//   Grid: (C/64, 8, batches); 256 threads.
__global__ __launch_bounds__(256) void blockify_kernel(
    const float* __restrict__ in, ushort_t* __restrict__ out, int C)
{
    __shared__ float t[64][65];
    const int k0 = blockIdx.y * 64, c0 = blockIdx.x * 64;
    const float* inb = in + (size_t)blockIdx.z * 512 * C;
    const int tid = threadIdx.x;
#pragma unroll
    for (int i = 0; i < 16; ++i) {
        int idx = tid + i * 256;
        int r = idx >> 6, c = idx & 63;
        t[r][c] = inb[(size_t)(k0 + r) * C + c0 + c];
    }
    __syncthreads();
    const size_t mbase = (size_t)blockIdx.z * C + c0;
    const int ml = tid & 63;
#pragma unroll
    for (int i = 0; i < 2; ++i) {
        int oct = (tid >> 6) + i * 4;          // k-octet 0..7
        size_t m = mbase + ml;
        int mt = (int)(m >> 7), mr = (int)(m & 127);
        int m16 = mr >> 4, col = mr & 15;
        int k = k0 + oct * 8;
        int it = k >> 5, q = (k >> 3) & 3;
        uint4 pk;
        pk.x = f2bf(t[oct * 8 + 0][ml]) | (f2bf(t[oct * 8 + 1][ml]) << 16);
        pk.y = f2bf(t[oct * 8 + 2][ml]) | (f2bf(t[oct * 8 + 3][ml]) << 16);
        pk.z = f2bf(t[oct * 8 + 4][ml]) | (f2bf(t[oct * 8 + 5][ml]) << 16);
        pk.w = f2bf(t[oct * 8 + 6][ml]) | (f2bf(t[oct * 8 + 7][ml]) << 16);
        size_t off = ((size_t)(mt * 16 + it) * 8 + m16) * 512 + (q * 16 + col) * 8;
        *(uint4*)&out[off] = pk;
    }
}

// ---------------------------------------------------------------------------
// Kernel 1: QKV GEMM (MFMA), BK=32, blocked contiguous staging, XCD swizzle.
//   v3: counted-vmcnt pipeline (T3+T4): prefetch depth 2, raw barriers,
//   vmcnt(4) at loop top keeps next tile's loads in flight (no drain).
//   v4: V written in pi-permuted row order so attn's PV A-fragments need
//   NO LDS round-trip.  Grid: (12, 128); 256 thr; 32 KB LDS.
// ---------------------------------------------------------------------------
__global__ __launch_bounds__(256) void qkv_gemm_kernel(
    const ushort_t* __restrict__ xtb, const ushort_t* __restrict__ WpTb,
    const float* __restrict__ bp,
    ushort_t* __restrict__ q_buf, ushort_t* __restrict__ kb,
    ushort_t* __restrict__ vb)
{
    __shared__ alignas(16) ushort_t Asub[2][8 * 512];   // 2 x 8 KB
    __shared__ alignas(16) ushort_t Bsub[2][8 * 512];   // 2 x 8 KB

    const int tid = threadIdx.x, w = tid >> 6, lane = tid & 63;
    const int quad = lane >> 4, col = lane & 15;
    const int wm = w >> 1, wn = w & 1;

    // XCD swizzle: all 12 n-tiles of one m-tile on one XCD
    const int lin = blockIdx.x + 12 * blockIdx.y;   // 0..1535
    const int xcd = lin & 7;
    const int rr  = lin >> 3;
    const int n0  = (rr % 12) * 128;
    const int m0  = ((rr / 12) * 8 + xcd) * 128;

    f32x4 acc[4][4];
#pragma unroll
    for (int i = 0; i < 4; ++i)
#pragma unroll
        for (int j = 0; j < 4; ++j) acc[i][j] = (f32x4){0.f, 0.f, 0.f, 0.f};

    const ushort_t* Ab = xtb  + (size_t)(m0 >> 7) * 65536 + (w * 2) * 512 + lane * 8;
    const ushort_t* Bb = WpTb + (size_t)(n0 >> 7) * 65536 + (w * 2) * 512 + lane * 8;

#define QKV_STAGE(buf, t)                                         \
    do {                                                          \
        async16(Ab + (t) * 4096,       &Asub[buf][(w * 2 + 0) * 512]); \
        async16(Ab + (t) * 4096 + 512, &Asub[buf][(w * 2 + 1) * 512]); \
        async16(Bb + (t) * 4096,       &Bsub[buf][(w * 2 + 0) * 512]); \
        async16(Bb + (t) * 4096 + 512, &Bsub[buf][(w * 2 + 1) * 512]); \
    } while (0)

    QKV_STAGE(0, 0);
    QKV_STAGE(1, 1);
    for (int it = 0; it < 16; ++it) {
        const int cur = it & 1;
        if (it < 15) { WAIT_VMCNT(4); } else { WAIT_VMCNT(0); }
        barrier_raw();                   // buf[cur] staged for all waves

        short8 af[4], bfr[4];
#pragma unroll
        for (int i = 0; i < 4; ++i) af[i]  = *(const short8*)&Asub[cur][(wm * 4 + i) * 512 + lane * 8];
#pragma unroll
        for (int j = 0; j < 4; ++j) bfr[j] = *(const short8*)&Bsub[cur][(wn * 4 + j) * 512 + lane * 8];
#pragma unroll
        for (int i = 0; i < 4; ++i)
#pragma unroll
            for (int j = 0; j < 4; ++j)
                acc[i][j] = __builtin_amdgcn_mfma_f32_16x16x32_bf16(af[i], bfr[j], acc[i][j], 0, 0, 0);

        if (it < 14) {
            barrier_raw();               // all waves done reading buf[cur]
            QKV_STAGE(cur, it + 2);
        }
    }
#undef QKV_STAGE

    // ---- epilogue: split q/k/v; q pre-scaled by QSCALE ----
    const int b = m0 >> 10, s0 = m0 & 1023;
    const size_t b8 = (size_t)b * HEADS;
#pragma unroll
    for (int j = 0; j < 4; ++j) {
        int nb = n0 + wn * 64 + j * 16;               // frag n base (wave-uniform)
        int h = nb / 192, rem = nb % 192;
        int type = rem >> 6, dbase = rem & 63;        // uniform per frag
        float bias = bp[nb + col];
        size_t bh = b8 + h;
        int d = dbase + col;
#pragma unroll
        for (int i = 0; i < 4; ++i) {
            int sb = s0 + wm * 64 + i * 16 + quad * 4;    // s for r=0
            f32x4 v = acc[i][j];
            if (type == 2) {
                // vb blocked + pi-permuted rows: slot tau for t=sb..sb+3 is
                // contiguous: tau&7 = ((sb>>4)&1)*4 + r, quad-slot = (sb>>2)&3
                unsigned lo = f2bf(v[0] + bias) | (f2bf(v[1] + bias) << 16);
                unsigned hi = f2bf(v[2] + bias) | (f2bf(v[3] + bias) << 16);
                uint2 pk; pk.x = lo; pk.y = hi;
                int itv = sb >> 6, sub = (d >> 4) * 2 + ((sb >> 5) & 1);
                size_t off = ((bh * 16 + itv) * 8 + sub) * 512
                           + (((sb >> 2) & 3) * 16 + (d & 15)) * 8
                           + ((sb >> 4) & 1) * 4;
                *(uint2*)&vb[off] = pk;
            } else if (type == 1) {
                // kb blocked: elem (bh,t,d): it=t>>6, sub=((t>>4)&3)*2+(d>>5)
#pragma unroll
                for (int r = 0; r < 4; ++r) {
                    int t = sb + r;
                    int itk = t >> 6, sub = ((t >> 4) & 3) * 2 + (d >> 5);
                    size_t off = ((bh * 16 + itk) * 8 + sub) * 512
                               + (((d >> 3) & 3) * 16 + (t & 15)) * 8 + (d & 7);
                    kb[off] = (ushort_t)f2bf(v[r] + bias);
                }
            } else {
#pragma unroll
                for (int r = 0; r < 4; ++r)
                    q_buf[(bh * SEQ + sb + r) * DHEAD + d] =
                        (ushort_t)f2bf((v[r] + bias) * QSCALE);
            }
        }
    }
}

// ---------------------------------------------------------------------------
// Kernel 2: MFMA flash attention; blocked contiguous K/V staging; dbuf;
//   unnormalized softmax via exp2 (q pre-scaled by log2e); S^T trick.
//   v4 (measured best, 51.3 us): ZERO P round-trip — V rows pi-permuted in
//   vb so each lane's S^T values ARE its PV A-fragment after exp2+pack.
//   2 waves x 4 q-groups; __syncthreads dbuf; 32 KB LDS -> 4 blocks/CU.
//   (R5 SW-pipeline and R6 4-wave variants both regressed; reverted.)
//   Grid: (bh=128, qtile=8); 128 threads.
// ---------------------------------------------------------------------------
__global__ __launch_bounds__(128) void attn_kernel(
    const ushort_t* __restrict__ q_buf, const ushort_t* __restrict__ kb,
    const ushort_t* __restrict__ vb, ushort_t* __restrict__ resb)
{
    __shared__ alignas(16) ushort_t Kf[2][8 * 512];   // ping-pong, 16 KB
    __shared__ alignas(16) ushort_t Vf[2][8 * 512];   // ping-pong, 16 KB

    const int tid  = threadIdx.x;
    const int w    = tid >> 6;            // 0..1
    const int lane = tid & 63;
    const int quad = lane >> 4;
    const int col  = lane & 15;

    const int bhid = blockIdx.x;          // 0..127
    const int b = bhid >> 3, h = bhid & 7;
    const int q0 = blockIdx.y * 128;
    const size_t bh = (size_t)b * HEADS + h;

    // Q B-frags for 4 groups (pre-scaled by QSCALE in qkv_gemm)
    // group g covers q rows q0 + w*64 + g*16 .. +15
    const ushort_t* qp = q_buf + ((bh * SEQ) + q0 + w * 64 + col) * DHEAD + quad * 8;
    short8 qf0[4], qf1[4];
#pragma unroll
    for (int g = 0; g < 4; ++g) {
        qf0[g] = *(const short8*)(qp + g * 16 * DHEAD);
        qf1[g] = *(const short8*)(qp + g * 16 * DHEAD + 32);
    }

    short8 ones;
#pragma unroll
    for (int i = 0; i < 8; ++i) ones[i] = (short)0x3F80;

    f32x4 O[4][4];
#pragma unroll
    for (int g = 0; g < 4; ++g)
#pragma unroll
        for (int i = 0; i < 4; ++i) O[g][i] = (f32x4){0.f, 0.f, 0.f, 0.f};
    f32x4 L[4];
#pragma unroll
    for (int g = 0; g < 4; ++g) L[g] = (f32x4){0.f, 0.f, 0.f, 0.f};

    // blocked contiguous staging pointers (wave w stages subs w*4+{0..3})
    const ushort_t* kaB = kb + (size_t)bh * 65536 + (w * 4) * 512 + lane * 8;
    const ushort_t* vaB = vb + (size_t)bh * 65536 + (w * 4) * 512 + lane * 8;

#define ATTN_STAGE(buf)                                            \
    do {                                                           \
        async16(kaB,        &Kf[buf][(w * 4 + 0) * 512]);          \
        async16(kaB + 512,  &Kf[buf][(w * 4 + 1) * 512]);          \
        async16(kaB + 1024, &Kf[buf][(w * 4 + 2) * 512]);          \
        async16(kaB + 1536, &Kf[buf][(w * 4 + 3) * 512]);          \
        async16(vaB,        &Vf[buf][(w * 4 + 0) * 512]);          \
        async16(vaB + 512,  &Vf[buf][(w * 4 + 1) * 512]);          \
        async16(vaB + 1024, &Vf[buf][(w * 4 + 2) * 512]);          \
        async16(vaB + 1536, &Vf[buf][(w * 4 + 3) * 512]);          \
        kaB += 4096;                                               \
        vaB += 4096;                                               \
    } while (0)

    ATTN_STAGE(0);

    for (int it = 0; it < 16; ++it) {
        const int cur = it & 1;
        const ushort_t* kc = Kf[cur];
        const ushort_t* vc = Vf[cur];
        __syncthreads();   // buf[cur] staged; prior readers of buf[cur^1] done
        if (it < 15) ATTN_STAGE(cur ^ 1);

        // ---- K frags to regs once; shared by all 4 groups ----
        short8 kf[8];
#pragma unroll
        for (int t16 = 0; t16 < 4; ++t16) {
            kf[2 * t16 + 0] = *(const short8*)&kc[(t16 * 2 + 0) * 512 + lane * 8];
            kf[2 * t16 + 1] = *(const short8*)&kc[(t16 * 2 + 1) * 512 + lane * 8];
        }

        // ---- per group: S^T = K Q^T; P fragments built IN REGISTERS ----
        // lane holds S^T[t=t16*16+quad*4+r][q=col]; under vb's pi-permutation
        // pf[0] = bf16(exp2(S[0][0..3]), exp2(S[1][0..3])), pf[1] = t16 2,3.
        short8 pf[4][2];
#pragma unroll
        for (int g = 0; g < 4; ++g) {
            f32x4 S[4];
            __builtin_amdgcn_s_setprio(1);
#pragma unroll
            for (int t16 = 0; t16 < 4; ++t16) {
                f32x4 a = (f32x4){0.f, 0.f, 0.f, 0.f};
                a = __builtin_amdgcn_mfma_f32_16x16x32_bf16(kf[2 * t16 + 0], qf0[g], a, 0, 0, 0);
                a = __builtin_amdgcn_mfma_f32_16x16x32_bf16(kf[2 * t16 + 1], qf1[g], a, 0, 0, 0);
                S[t16] = a;
            }
            __builtin_amdgcn_s_setprio(0);
            union { uint4 u; short8 s; } p0, p1;
            p0.u.x = pack_bf16_trunc(fast_exp2(S[0][0]), fast_exp2(S[0][1]));
            p0.u.y = pack_bf16_trunc(fast_exp2(S[0][2]), fast_exp2(S[0][3]));
            p0.u.z = pack_bf16_trunc(fast_exp2(S[1][0]), fast_exp2(S[1][1]));
            p0.u.w = pack_bf16_trunc(fast_exp2(S[1][2]), fast_exp2(S[1][3]));
            p1.u.x = pack_bf16_trunc(fast_exp2(S[2][0]), fast_exp2(S[2][1]));
            p1.u.y = pack_bf16_trunc(fast_exp2(S[2][2]), fast_exp2(S[2][3]));
            p1.u.z = pack_bf16_trunc(fast_exp2(S[3][0]), fast_exp2(S[3][1]));
            p1.u.w = pack_bf16_trunc(fast_exp2(S[3][2]), fast_exp2(S[3][3]));
            pf[g][0] = p0.s;
            pf[g][1] = p1.s;
        }

        // ---- O += P V ; V frags read once/d16, shared by 4 groups ----
#pragma unroll
        for (int d16 = 0; d16 < 4; ++d16) {
            const short8 v0 = *(const short8*)&vc[(d16 * 2 + 0) * 512 + lane * 8];
            const short8 v1 = *(const short8*)&vc[(d16 * 2 + 1) * 512 + lane * 8];
            __builtin_amdgcn_s_setprio(1);
#pragma unroll
            for (int g = 0; g < 4; ++g) {
                O[g][d16] = __builtin_amdgcn_mfma_f32_16x16x32_bf16(pf[g][0], v0, O[g][d16], 0, 0, 0);
                O[g][d16] = __builtin_amdgcn_mfma_f32_16x16x32_bf16(pf[g][1], v1, O[g][d16], 0, 0, 0);
            }
            __builtin_amdgcn_s_setprio(0);
        }
#pragma unroll
        for (int g = 0; g < 4; ++g) {
            L[g] = __builtin_amdgcn_mfma_f32_16x16x32_bf16(pf[g][0], ones, L[g], 0, 0, 0);
            L[g] = __builtin_amdgcn_mfma_f32_16x16x32_bf16(pf[g][1], ones, L[g], 0, 0, 0);
        }
    }
#undef ATTN_STAGE

    // ---- epilogue: O / L -> resb in out_gemm's blocked order ----
    const int mt = b * 8 + (q0 >> 7);
#pragma unroll
    for (int g = 0; g < 4; ++g) {
        const int m16 = w * 4 + g;
#pragma unroll
        for (int r = 0; r < 4; ++r) {
            float inv = 1.f / L[g][r];
            const int mcol = quad * 4 + r;
#pragma unroll
            for (int d16 = 0; d16 < 4; ++d16) {
                int itk = h * 2 + (d16 >> 1);
                int kq = (d16 & 1) * 2 + (col >> 3);
                size_t off = ((size_t)(mt * 16 + itk) * 8 + m16) * 512
                           + (kq * 16 + mcol) * 8 + (col & 7);
                resb[off] = (ushort_t)f2bf(O[g][d16][r] * inv);
            }
        }
    }
}

// ---------------------------------------------------------------------------
// Kernel 3: out GEMM (MFMA), BK=32, blocked staging, XCD swizzle.
//   v3: counted-vmcnt pipeline (same as qkv).
//   v4: COALESCED epilogue — old store had n varying per lane (4 KB/lane
//   stride, 64 cachelines per instr).  Now: transpose acc through a 32 KB
//   LDS overlay (reusing Asub/Bsub) so each store/load instruction covers
//   2 n-rows x 128 contiguous s (2 x 512 B segments).
//   Grid: (4, 128); 32 KB LDS.
// ---------------------------------------------------------------------------
__global__ __launch_bounds__(256) void out_gemm_kernel(
    const ushort_t* __restrict__ resb, const ushort_t* __restrict__ WoTb,
    const float* __restrict__ bo, const float* __restrict__ x,
    float* __restrict__ out)
{
    __shared__ alignas(16) ushort_t SMEM[2 * 2 * 8 * 512];   // 32 KB
    ushort_t (*Asub)[8 * 512] = (ushort_t (*)[8 * 512])(SMEM);
    ushort_t (*Bsub)[8 * 512] = (ushort_t (*)[8 * 512])(SMEM + 2 * 8 * 512);
    float* tb = (float*)SMEM;            // epilogue overlay [32][132] fp32

    const int tid = threadIdx.x, w = tid >> 6, lane = tid & 63;
    const int quad = lane >> 4, col = lane & 15;
    const int wm = w >> 1, wn = w & 1;

    const int lin = blockIdx.x + 4 * blockIdx.y;    // 0..511
    const int xcd = lin & 7;
    const int rr  = lin >> 3;
    const int n0  = (rr & 3) * 128;
    const int m0  = ((rr >> 2) * 8 + xcd) * 128;

    f32x4 acc[4][4];
#pragma unroll
    for (int i = 0; i < 4; ++i)
#pragma unroll
        for (int j = 0; j < 4; ++j) acc[i][j] = (f32x4){0.f, 0.f, 0.f, 0.f};

    const ushort_t* Ab = resb + (size_t)(m0 >> 7) * 65536 + (w * 2) * 512 + lane * 8;
    const ushort_t* Bb = WoTb + (size_t)(n0 >> 7) * 65536 + (w * 2) * 512 + lane * 8;

#define OUT_STAGE(buf, t)                                         \
    do {                                                          \
        async16(Ab + (t) * 4096,       &Asub[buf][(w * 2 + 0) * 512]); \
        async16(Ab + (t) * 4096 + 512, &Asub[buf][(w * 2 + 1) * 512]); \
        async16(Bb + (t) * 4096,       &Bsub[buf][(w * 2 + 0) * 512]); \
        async16(Bb + (t) * 4096 + 512, &Bsub[buf][(w * 2 + 1) * 512]); \
    } while (0)

    OUT_STAGE(0, 0);
    OUT_STAGE(1, 1);
    for (int it = 0; it < 16; ++it) {
        const int cur = it & 1;
        if (it < 15) { WAIT_VMCNT(4); } else { WAIT_VMCNT(0); }
        barrier_raw();

        short8 af[4], bfr[4];
#pragma unroll
        for (int i = 0; i < 4; ++i) af[i]  = *(const short8*)&Asub[cur][(wm * 4 + i) * 512 + lane * 8];
#pragma unroll
        for (int j = 0; j < 4; ++j) bfr[j] = *(const short8*)&Bsub[cur][(wn * 4 + j) * 512 + lane * 8];
#pragma unroll
        for (int i = 0; i < 4; ++i)
#pragma unroll
            for (int j = 0; j < 4; ++j)
                acc[i][j] = __builtin_amdgcn_mfma_f32_16x16x32_bf16(af[i], bfr[j], acc[i][j], 0, 0, 0);

        if (it < 14) {
            barrier_raw();
            OUT_STAGE(cur, it + 2);
        }
    }
#undef OUT_STAGE

    // ---- coalesced epilogue via LDS transpose ----
    // Per j-pass: all waves stage acc[:,j] (32 n x 128 s fp32) into tb,
    // then each wave streams 2 n-rows x 128 contiguous s per instruction.
    const int b = m0 >> 10, s0 = m0 & 1023;
    const int half = lane >> 5, l32 = lane & 31;
#pragma unroll
    for (int j = 0; j < 4; ++j) {
        __syncthreads();   // previous pass readers / main-loop readers done
#pragma unroll
        for (int i = 0; i < 4; ++i) {
            f32x4 v = acc[i][j];
            float* dst = &tb[(wn * 16 + col) * 132 + wm * 64 + i * 16 + quad * 4];
            dst[0] = v[0]; dst[1] = v[1]; dst[2] = v[2]; dst[3] = v[3];
        }
        __syncthreads();   // tb fully staged
#pragma unroll
        for (int p = 0; p < 4; ++p) {
            int nl = w * 8 + p * 2 + half;                 // 0..31
            int n = n0 + j * 16 + (nl & 15) + (nl >> 4) * 64;
            float4 t4 = *(const float4*)&tb[nl * 132 + l32 * 4];
            size_t o = ((size_t)b * CDIM + n) * SEQ + s0 + l32 * 4;
            float4 xr = *(const float4*)&x[o];
            float bias = bo[n];
            float4 ov;
            ov.x = t4.x + bias + xr.x;
            ov.y = t4.y + bias + xr.y;
            ov.z = t4.z + bias + xr.z;
            ov.w = t4.w + bias + xr.w;
            *(float4*)&out[o] = ov;
        }
    }
}

// ---------------------------------------------------------------------------
extern "C" void kernel_launch(void* const* d_in, const int* in_sizes, int n_in,
                              void* d_out, int out_size, void* d_ws, size_t ws_size,
                              hipStream_t stream) {
    const float* x  = (const float*)d_in[0];   // (16, 512, 32, 32) fp32
    const float* Wp = (const float*)d_in[1];   // (512, 1536) fp32
    const float* bp = (const float*)d_in[2];   // (1536,) fp32
    const float* Wo = (const float*)d_in[3];   // (512, 512) fp32
    const float* bo = (const float*)d_in[4];   // (512,) fp32
    float* out = (float*)d_out;                // (16, 512, 32, 32) fp32

    // ws layout (ushort units), ~86 MB
    ushort_t* xtb   = (ushort_t*)d_ws;               // blocked [mt][it][sub][lane][8]
    ushort_t* WpTb  = xtb   + (size_t)8388608;
    ushort_t* WoTb  = WpTb  + (size_t)786432;
    ushort_t* q_buf = WoTb  + (size_t)262144;        // row-major [bh][s][d]
    ushort_t* kb    = q_buf + (size_t)8388608;       // attn-blocked
    ushort_t* vb    = kb    + (size_t)8388608;       // attn-blocked, pi-permuted rows
    ushort_t* resb  = vb    + (size_t)8388608;       // out_gemm-blocked

    blockify_kernel<<<dim3(16, 8, 16), 256, 0, stream>>>(x,  xtb,  1024);
    blockify_kernel<<<dim3(24, 8, 1),  256, 0, stream>>>(Wp, WpTb, 1536);
    blockify_kernel<<<dim3(8, 8, 1),   256, 0, stream>>>(Wo, WoTb, 512);
    qkv_gemm_kernel<<<dim3(12, 128), 256, 0, stream>>>(xtb, WpTb, bp, q_buf, kb, vb);
    attn_kernel<<<dim3(128, 8), 128, 0, stream>>>(q_buf, kb, vb, resb);
    out_gemm_kernel<<<dim3(4, 128), 256, 0, stream>>>(resb, WoTb, bo, x, out);
}